// Round 9
// baseline (834.797 us; speedup 1.0000x reference)
//
#include <hip/hip_runtime.h>
#include <stdint.h>

#define NP 1024
#define NV 49408
#define ND 512
// A,B packed: [row][hi(512)|lo(512)] bf16 -> physical K=1024 (2048 B/row).
// Logical K=1536, 3-term split, 32-k steps -> 48 tiles:
//   A phys byte = (t & 31) * 64           (ah x16, al x16, ah x16)
//   B phys byte = (t & 15) * 64 + (t >= 32 ? 1024 : 0)   (bh, bh, bl)
#define NTILE 48

typedef __attribute__((ext_vector_type(8))) __bf16 bf16x8;
typedef __attribute__((ext_vector_type(4))) float f32x4;
typedef __attribute__((ext_vector_type(4))) int i32x4;

__device__ inline unsigned long long pack_sv(float s, unsigned v) {
  unsigned u = __float_as_uint(s);
  u = (u & 0x80000000u) ? ~u : (u | 0x80000000u);  // orderable map
  return ((unsigned long long)u << 32) | (unsigned long long)v;
}

// Split each f32 row into bf16 hi/lo halves, layout [row][hi(512)|lo(512)];
// optionally emit exact f32 sum of squares per row.
__global__ __launch_bounds__(256) void pack_rows_k(const float* __restrict__ src,
                                                   __bf16* __restrict__ dst,
                                                   float* __restrict__ sumsq,
                                                   int nrows) {
  int lane = threadIdx.x & 63;
  int row = blockIdx.x * 4 + (threadIdx.x >> 6);
  if (row >= nrows) return;
  const float* r = src + (size_t)row * ND + lane * 8;
  float4 x0 = *(const float4*)r;
  float4 x1 = *(const float4*)(r + 4);
  float xs[8] = {x0.x, x0.y, x0.z, x0.w, x1.x, x1.y, x1.z, x1.w};
  bf16x8 hi, lo;
  float ss = 0.f;
#pragma unroll
  for (int j = 0; j < 8; ++j) {
    float x = xs[j];
    ss += x * x;
    __bf16 h = (__bf16)x;
    hi[j] = h;
    lo[j] = (__bf16)(x - (float)h);   // exact residual, then RTNE to bf16
  }
  __bf16* drow = dst + (size_t)row * 1024 + lane * 8;
  *(bf16x8*)drow = hi;
  *(bf16x8*)(drow + 512) = lo;
  if (sumsq != nullptr) {
#pragma unroll
    for (int m = 1; m < 64; m <<= 1) ss += __shfl_xor(ss, m);
    if (lane == 0) sumsq[row] = ss;
  }
}

// ---- 128x128 tile, BK=32, 4 waves, 4 blocks/CU -----------------------------
// A-fragments: direct global->register (A is 2 MB, L2/L1-resident; no LDS),
// double-buffered one phase ahead. B: LDS 3 regions x 8 KB, depth-2 rotation.
// Per phase: [4x A-prefetch(t+1)] [2x gll16 B-stage(t+2) -> region (p+2)%3]
// [4x ds_read_b128 b(t) from region p%3] [s_waitcnt vmcnt(6) lgkmcnt(0)]
// [16 MFMA] [s_barrier].  vmcnt(6) leaves exactly this phase's 6 loads ->
// forces A(t) + Bstage(t) complete BEFORE the barrier, which gives cross-wave
// visibility for next phase's reads; single barrier per phase suffices.
// B slot swizzle (R6-verified, 0 conflicts): 16B-slot
//   q(row,c16) = (row>>1)*8 + (row&1)*4 + ((c16 + (row>>1)) & 3)

__device__ __attribute__((always_inline)) static inline
void gll16(const char* src, char* dst) {
  __builtin_amdgcn_global_load_lds(
      (const __attribute__((address_space(1))) void*)src,
      (__attribute__((address_space(3))) void*)dst, 16, 0, 0);
}

__device__ __attribute__((always_inline)) static inline
bf16x8 lds_read(unsigned addr) {
  i32x4 d;
  asm volatile("ds_read_b128 %0, %1" : "=v"(d) : "v"(addr));
  return __builtin_bit_cast(bf16x8, d);
}

#define FENCE asm volatile("" ::: "memory")

template <int PH>
__device__ __attribute__((always_inline)) static inline
void phase_op(f32x4 (&acc)[4][4], bf16x8 (&aE)[4], bf16x8 (&aO)[4],
              const char* Ab, const int (&voffA)[4],
              const char* srcBt, char* stB, unsigned bRead, int p) {
  constexpr int R = PH % 3;
  constexpr int RS = (PH + 2) % 3;
  const int kA = ((p + 1) & 31) * 64;                          // A tile p+1
  const int t2 = p + 2;
  const int kB = (t2 & 15) * 64 + (t2 >= 32 ? 1024 : 0);       // B tile p+2
  bf16x8 (&aN)[4] = (PH % 2 == 0) ? aO : aE;   // prefetch target
  bf16x8 (&aC)[4] = (PH % 2 == 0) ? aE : aO;   // compute source
  // A prefetch for next phase (global, L2-hit; latency = 1 phase)
#pragma unroll
  for (int m = 0; m < 4; ++m)
    aN[m] = *(const bf16x8*)(Ab + voffA[m] + kA);
  // B stage for phase p+2 (region RS died at phase p-1)
  gll16(srcBt + kB, stB + RS * 8192);
  gll16(srcBt + kB + 131072, stB + RS * 8192 + 4096);
  // B fragment reads for this phase
  bf16x8 b[4];
#pragma unroll
  for (int n = 0; n < 4; ++n)
    b[n] = lds_read(bRead + R * 8192 + n * 1024);
  asm volatile("s_waitcnt vmcnt(6) lgkmcnt(0)" ::: "memory");
  __builtin_amdgcn_sched_barrier(0);
  __builtin_amdgcn_s_setprio(1);
#pragma unroll
  for (int m = 0; m < 4; ++m)
#pragma unroll
    for (int n = 0; n < 4; ++n)
      acc[m][n] = __builtin_amdgcn_mfma_f32_16x16x32_bf16(aC[m], b[n], acc[m][n], 0, 0, 0);
  __builtin_amdgcn_s_setprio(0);
  FENCE;
  __builtin_amdgcn_s_barrier();
  FENCE;
}

__global__ __launch_bounds__(256, 4) void gemm_argmin_k(const __bf16* __restrict__ A,
                                                        const __bf16* __restrict__ B,
                                                        const float* __restrict__ b2,
                                                        unsigned long long* __restrict__ best) {
  __shared__ __align__(16) char lds[24576];
  const int tid = threadIdx.x;
  const int lane = tid & 63;
  const int wid = tid >> 6;   // 0..3
  const int wm = wid >> 1;    // 2 wave-rows (64 rows each)
  const int wn = wid & 1;     // 2 wave-cols (64 cols each)

  // XCD-chunk swizzle (3088 % 8 == 0 -> bijective): 8 M-blocks of a B-panel
  // land on one XCD -> panel fetched into L2 once (R6: FETCH 606->64 MB).
  const int d = blockIdx.x;
  const int o = (d & 7) * 386 + (d >> 3);
  const int bm = (o & 7) * 128;
  const int bn = (o >> 3) * 128;

  const int r = lane & 15, g = lane >> 4;
  const int rh = r >> 1;
  const unsigned lds0 =
      (unsigned)(uintptr_t)(const __attribute__((address_space(3))) char*)(const char*)lds;
  const unsigned bRead = lds0 + wn * 4096 + rh * 128 + (r & 1) * 64 + (((g + rh) & 3) << 4);

  // A per-lane byte offsets (frag m: row = bm + wm*64 + m*16 + r, col g*16)
  const char* Ab = (const char*)A + (size_t)bm * 2048;
  int voffA[4];
#pragma unroll
  for (int m = 0; m < 4; ++m) voffA[m] = (wm * 64 + m * 16 + r) * 2048 + g * 16;

  // B stage-side lane mapping (inverse of the slot swizzle); 256 threads
  // cover 512 slots of the 8 KB region (rows 0-63 and +64 via 2nd gll16)
  const int srow = 2 * (tid >> 3) + ((tid >> 2) & 1);
  const int sc16 = ((tid & 3) - (tid >> 3)) & 3;
  const char* srcBt = (const char*)B + (size_t)(bn + srow) * 2048 + sc16 * 16;
  char* stB = (char*)lds + tid * 16;

  f32x4 acc[4][4] = {};
  bf16x8 aE[4], aO[4];

  // prologue: A(0) -> aE, Bstage(0)->R0, Bstage(1)->R1; drain A(0)+Bst(0)
#pragma unroll
  for (int m = 0; m < 4; ++m)
    aE[m] = *(const bf16x8*)(Ab + voffA[m] + 0);
  gll16(srcBt + 0, stB + 0);
  gll16(srcBt + 0 + 131072, stB + 4096);
  gll16(srcBt + 64, stB + 8192);
  gll16(srcBt + 64 + 131072, stB + 8192 + 4096);
  asm volatile("s_waitcnt vmcnt(2)" ::: "memory");
  FENCE;
  __builtin_amdgcn_s_barrier();
  FENCE;

#pragma unroll 1
  for (int it = 0; it < 8; ++it) {
    const int p0 = 6 * it;
    phase_op<0>(acc, aE, aO, Ab, voffA, srcBt, stB, bRead, p0 + 0);
    phase_op<1>(acc, aE, aO, Ab, voffA, srcBt, stB, bRead, p0 + 1);
    phase_op<2>(acc, aE, aO, Ab, voffA, srcBt, stB, bRead, p0 + 2);
    phase_op<3>(acc, aE, aO, Ab, voffA, srcBt, stB, bRead, p0 + 3);
    phase_op<4>(acc, aE, aO, Ab, voffA, srcBt, stB, bRead, p0 + 4);
    phase_op<5>(acc, aE, aO, Ab, voffA, srcBt, stB, bRead, p0 + 5);
  }

  // epilogue: fused argmin. C/D map: col = lane&15, row = (lane>>4)*4 + reg.
  float bb[4];
#pragma unroll
  for (int n = 0; n < 4; ++n) bb[n] = b2[bn + wn * 64 + n * 16 + r];
#pragma unroll
  for (int m = 0; m < 4; ++m) {
#pragma unroll
    for (int reg = 0; reg < 4; ++reg) {
      unsigned long long pk = ~0ull;
#pragma unroll
      for (int n = 0; n < 4; ++n) {
        float s = bb[n] - 2.0f * acc[m][n][reg];
        unsigned long long cand = pack_sv(s, (unsigned)(bn + wn * 64 + n * 16 + r));
        pk = (cand < pk) ? cand : pk;
      }
#pragma unroll
      for (int msk = 1; msk < 16; msk <<= 1) {
        unsigned long long o2 = __shfl_xor(pk, msk);
        pk = (o2 < pk) ? o2 : pk;
      }
      if (r == 0) atomicMin(&best[bm + wm * 64 + m * 16 + g * 4 + reg], pk);
    }
  }
}

// Fallback (small ws): exact fp32 squared distance, fused argmin.
__global__ __launch_bounds__(256) void naive_argmin_k(const float* __restrict__ A,
                                                      const float* __restrict__ B,
                                                      unsigned long long* __restrict__ best) {
  __shared__ float arow[ND];
  int p = blockIdx.y;
  unsigned v = blockIdx.x * 256 + threadIdx.x;
  for (int i = threadIdx.x; i < ND; i += 256) arow[i] = A[(size_t)p * ND + i];
  __syncthreads();
  const float4* br = (const float4*)(B + (size_t)v * ND);
  float s = 0.f;
#pragma unroll 4
  for (int i = 0; i < ND / 4; ++i) {
    float4 b = br[i];
    const float4 a = *(const float4*)&arow[i * 4];
    float d0 = a.x - b.x, d1 = a.y - b.y, d2 = a.z - b.z, d3 = a.w - b.w;
    s += d0 * d0 + d1 * d1 + d2 * d2 + d3 * d3;
  }
  unsigned long long pk = pack_sv(s, v);
#pragma unroll
  for (int msk = 1; msk < 64; msk <<= 1) {
    unsigned long long o = __shfl_xor(pk, msk);
    pk = (o < pk) ? o : pk;
  }
  if ((threadIdx.x & 63) == 0) atomicMin(&best[p], pk);
}

// Gather winning rows + ids (ids written as float, d_out is read as flat f32).
__global__ __launch_bounds__(128) void gather_k(const unsigned long long* __restrict__ best,
                                                const float* __restrict__ clip,
                                                float* __restrict__ out) {
  int p = blockIdx.x;
  unsigned long long pk = best[p];
  unsigned v = (unsigned)(pk & 0xffffffffull);
  const float4* src = (const float4*)(clip + (size_t)v * ND);
  float4* dst = (float4*)(out + (size_t)p * ND);
  dst[threadIdx.x] = src[threadIdx.x];
  if (threadIdx.x == 0) out[(size_t)NP * ND + p] = (float)v;
}

extern "C" void kernel_launch(void* const* d_in, const int* in_sizes, int n_in,
                              void* d_out, int out_size, void* d_ws, size_t ws_size,
                              hipStream_t stream) {
  const float* prompt = (const float*)d_in[0];
  const float* clip = (const float*)d_in[1];
  float* out = (float*)d_out;

  // workspace layout
  size_t off = 0;
  unsigned long long* best = (unsigned long long*)d_ws;
  off += (size_t)NP * 8;
  float* b2 = (float*)((char*)d_ws + off);
  off += (size_t)NV * 4;
  off = (off + 255) & ~(size_t)255;
  __bf16* Ap = (__bf16*)((char*)d_ws + off);
  off += (size_t)NP * 1024 * 2;                // 2 MiB  [hi|lo]
  __bf16* Bp = (__bf16*)((char*)d_ws + off);
  off += (size_t)NV * 1024 * 2;                // 96.5 MiB [hi|lo]
  const size_t need = off;

  if (ws_size >= need) {
    hipMemsetAsync(best, 0xFF, (size_t)NP * 8, stream);
    pack_rows_k<<<NP / 4, 256, 0, stream>>>(prompt, Ap, nullptr, NP);
    pack_rows_k<<<NV / 4, 256, 0, stream>>>(clip, Bp, b2, NV);
    gemm_argmin_k<<<dim3(8 * 386), 256, 0, stream>>>(Ap, Bp, b2, best);
    gather_k<<<NP, 128, 0, stream>>>(best, clip, out);
  } else {
    // fallback: exact fp32, needs only the 8 KiB `best` array
    hipMemsetAsync(best, 0xFF, (size_t)NP * 8, stream);
    dim3 grid(NV / 256, NP);
    naive_argmin_k<<<grid, 256, 0, stream>>>(prompt, clip, best);
    gather_k<<<NP, 128, 0, stream>>>(best, clip, out);
  }
}

// Round 10
// 379.870 us; speedup vs baseline: 2.1976x; 2.1976x over previous
//
#include <hip/hip_runtime.h>
#include <stdint.h>

#define NP 1024
#define NV 49408
#define ND 512
// A,B packed: [row][hi(512)|lo(512)] bf16 -> physical K=1024 (2048 B/row).
// Logical K=1536, 3-term split, 32-k steps -> 48 tiles:
//   A phys byte = (t & 31) * 64           (ah x16, al x16, ah x16)
//   B phys byte = (t & 15) * 64 + (t >= 32 ? 1024 : 0)   (bh, bh, bl)
#define NTILE 48

typedef __attribute__((ext_vector_type(8))) __bf16 bf16x8;
typedef __attribute__((ext_vector_type(4))) float f32x4;
typedef __attribute__((ext_vector_type(4))) int i32x4;

__device__ inline unsigned long long pack_sv(float s, unsigned v) {
  unsigned u = __float_as_uint(s);
  u = (u & 0x80000000u) ? ~u : (u | 0x80000000u);  // orderable map
  return ((unsigned long long)u << 32) | (unsigned long long)v;
}

// Split each f32 row into bf16 hi/lo halves, layout [row][hi(512)|lo(512)];
// optionally emit exact f32 sum of squares per row.
__global__ __launch_bounds__(256) void pack_rows_k(const float* __restrict__ src,
                                                   __bf16* __restrict__ dst,
                                                   float* __restrict__ sumsq,
                                                   int nrows) {
  int lane = threadIdx.x & 63;
  int row = blockIdx.x * 4 + (threadIdx.x >> 6);
  if (row >= nrows) return;
  const float* r = src + (size_t)row * ND + lane * 8;
  float4 x0 = *(const float4*)r;
  float4 x1 = *(const float4*)(r + 4);
  float xs[8] = {x0.x, x0.y, x0.z, x0.w, x1.x, x1.y, x1.z, x1.w};
  bf16x8 hi, lo;
  float ss = 0.f;
#pragma unroll
  for (int j = 0; j < 8; ++j) {
    float x = xs[j];
    ss += x * x;
    __bf16 h = (__bf16)x;
    hi[j] = h;
    lo[j] = (__bf16)(x - (float)h);   // exact residual, then RTNE to bf16
  }
  __bf16* drow = dst + (size_t)row * 1024 + lane * 8;
  *(bf16x8*)drow = hi;
  *(bf16x8*)(drow + 512) = lo;
  if (sumsq != nullptr) {
#pragma unroll
    for (int m = 1; m < 64; m <<= 1) ss += __shfl_xor(ss, m);
    if (lane == 0) sumsq[row] = ss;
  }
}

// ---- 128x128 tile, BK=32, 4 waves, 3 blocks/CU -----------------------------
// A-fragments: direct global->register (A is 2 MB, L1/L2-resident; no LDS),
// double-buffered one phase ahead. B: LDS 3 regions x 8 KB, depth-2 rotation.
// Per phase: [4x A-prefetch(t+1)] [2x gll16 B-stage(t+2) -> region (p+2)%3]
// [4x ds_read_b128 b(t) from region p%3] [s_waitcnt vmcnt(6) lgkmcnt(0)]
// [16 MFMA] [s_barrier].  vmcnt(6) leaves exactly this phase's 6 loads ->
// forces A(t) + Bstage(t) complete BEFORE the barrier, which gives cross-wave
// visibility for next phase's reads; single barrier per phase suffices.
// REGISTER BUDGET (R9 lesson): acc=64 AGPR + ~75 arch VGPR counts against the
// UNIFIED file; launch_bounds(256,4) -> 128 cap -> catastrophic scratch spill
// (WRITE_SIZE 1.5 GB). (256,3) -> 170 cap -> fits, 3 blocks/CU.
// B slot swizzle (R6-verified, 0 conflicts): 16B-slot
//   q(row,c16) = (row>>1)*8 + (row&1)*4 + ((c16 + (row>>1)) & 3)

__device__ __attribute__((always_inline)) static inline
void gll16(const char* src, char* dst) {
  __builtin_amdgcn_global_load_lds(
      (const __attribute__((address_space(1))) void*)src,
      (__attribute__((address_space(3))) void*)dst, 16, 0, 0);
}

__device__ __attribute__((always_inline)) static inline
bf16x8 lds_read(unsigned addr) {
  i32x4 d;
  asm volatile("ds_read_b128 %0, %1" : "=v"(d) : "v"(addr));
  return __builtin_bit_cast(bf16x8, d);
}

#define FENCE asm volatile("" ::: "memory")

template <int PH>
__device__ __attribute__((always_inline)) static inline
void phase_op(f32x4 (&acc)[4][4], bf16x8 (&aE)[4], bf16x8 (&aO)[4],
              const char* Ab, const int (&voffA)[4],
              const char* srcBt, char* stB, unsigned bRead, int p) {
  constexpr int R = PH % 3;
  constexpr int RS = (PH + 2) % 3;
  const int kA = ((p + 1) & 31) * 64;                          // A tile p+1
  const int t2 = p + 2;
  const int kB = (t2 & 15) * 64 + (t2 >= 32 ? 1024 : 0);       // B tile p+2
  bf16x8 (&aN)[4] = (PH % 2 == 0) ? aO : aE;   // prefetch target
  bf16x8 (&aC)[4] = (PH % 2 == 0) ? aE : aO;   // compute source
  // A prefetch for next phase (global, L2-hit; latency = 1 phase)
#pragma unroll
  for (int m = 0; m < 4; ++m)
    aN[m] = *(const bf16x8*)(Ab + voffA[m] + kA);
  // B stage for phase p+2 (region RS died at phase p-1)
  gll16(srcBt + kB, stB + RS * 8192);
  gll16(srcBt + kB + 131072, stB + RS * 8192 + 4096);
  // B fragment reads for this phase
  bf16x8 b[4];
#pragma unroll
  for (int n = 0; n < 4; ++n)
    b[n] = lds_read(bRead + R * 8192 + n * 1024);
  asm volatile("s_waitcnt vmcnt(6) lgkmcnt(0)" ::: "memory");
  __builtin_amdgcn_sched_barrier(0);
  __builtin_amdgcn_s_setprio(1);
#pragma unroll
  for (int m = 0; m < 4; ++m)
#pragma unroll
    for (int n = 0; n < 4; ++n)
      acc[m][n] = __builtin_amdgcn_mfma_f32_16x16x32_bf16(aC[m], b[n], acc[m][n], 0, 0, 0);
  __builtin_amdgcn_s_setprio(0);
  FENCE;
  __builtin_amdgcn_s_barrier();
  FENCE;
}

__global__ __launch_bounds__(256, 3) void gemm_argmin_k(const __bf16* __restrict__ A,
                                                        const __bf16* __restrict__ B,
                                                        const float* __restrict__ b2,
                                                        unsigned long long* __restrict__ best) {
  __shared__ __align__(16) char lds[24576];
  const int tid = threadIdx.x;
  const int lane = tid & 63;
  const int wid = tid >> 6;   // 0..3
  const int wm = wid >> 1;    // 2 wave-rows (64 rows each)
  const int wn = wid & 1;     // 2 wave-cols (64 cols each)

  // XCD-chunk swizzle (3088 % 8 == 0 -> bijective): 8 M-blocks of a B-panel
  // land on one XCD -> panel fetched into L2 once (R6: FETCH 606->64 MB).
  const int d = blockIdx.x;
  const int o = (d & 7) * 386 + (d >> 3);
  const int bm = (o & 7) * 128;
  const int bn = (o >> 3) * 128;

  const int r = lane & 15, g = lane >> 4;
  const int rh = r >> 1;
  const unsigned lds0 =
      (unsigned)(uintptr_t)(const __attribute__((address_space(3))) char*)(const char*)lds;
  const unsigned bRead = lds0 + wn * 4096 + rh * 128 + (r & 1) * 64 + (((g + rh) & 3) << 4);

  // A per-lane byte offsets (frag m: row = bm + wm*64 + m*16 + r, col g*16)
  const char* Ab = (const char*)A + (size_t)bm * 2048;
  int voffA[4];
#pragma unroll
  for (int m = 0; m < 4; ++m) voffA[m] = (wm * 64 + m * 16 + r) * 2048 + g * 16;

  // B stage-side lane mapping (inverse of the slot swizzle); 256 threads
  // cover 512 slots of the 8 KB region (rows 0-63 and +64 via 2nd gll16)
  const int srow = 2 * (tid >> 3) + ((tid >> 2) & 1);
  const int sc16 = ((tid & 3) - (tid >> 3)) & 3;
  const char* srcBt = (const char*)B + (size_t)(bn + srow) * 2048 + sc16 * 16;
  char* stB = (char*)lds + tid * 16;

  f32x4 acc[4][4] = {};
  bf16x8 aE[4], aO[4];

  // prologue: A(0) -> aE, Bstage(0)->R0, Bstage(1)->R1; drain A(0)+Bst(0)
#pragma unroll
  for (int m = 0; m < 4; ++m)
    aE[m] = *(const bf16x8*)(Ab + voffA[m] + 0);
  gll16(srcBt + 0, stB + 0);
  gll16(srcBt + 0 + 131072, stB + 4096);
  gll16(srcBt + 64, stB + 8192);
  gll16(srcBt + 64 + 131072, stB + 8192 + 4096);
  asm volatile("s_waitcnt vmcnt(2)" ::: "memory");
  FENCE;
  __builtin_amdgcn_s_barrier();
  FENCE;

#pragma unroll 1
  for (int it = 0; it < 8; ++it) {
    const int p0 = 6 * it;
    phase_op<0>(acc, aE, aO, Ab, voffA, srcBt, stB, bRead, p0 + 0);
    phase_op<1>(acc, aE, aO, Ab, voffA, srcBt, stB, bRead, p0 + 1);
    phase_op<2>(acc, aE, aO, Ab, voffA, srcBt, stB, bRead, p0 + 2);
    phase_op<3>(acc, aE, aO, Ab, voffA, srcBt, stB, bRead, p0 + 3);
    phase_op<4>(acc, aE, aO, Ab, voffA, srcBt, stB, bRead, p0 + 4);
    phase_op<5>(acc, aE, aO, Ab, voffA, srcBt, stB, bRead, p0 + 5);
  }

  // epilogue: fused argmin. C/D map: col = lane&15, row = (lane>>4)*4 + reg.
  float bb[4];
#pragma unroll
  for (int n = 0; n < 4; ++n) bb[n] = b2[bn + wn * 64 + n * 16 + r];
#pragma unroll
  for (int m = 0; m < 4; ++m) {
#pragma unroll
    for (int reg = 0; reg < 4; ++reg) {
      unsigned long long pk = ~0ull;
#pragma unroll
      for (int n = 0; n < 4; ++n) {
        float s = bb[n] - 2.0f * acc[m][n][reg];
        unsigned long long cand = pack_sv(s, (unsigned)(bn + wn * 64 + n * 16 + r));
        pk = (cand < pk) ? cand : pk;
      }
#pragma unroll
      for (int msk = 1; msk < 16; msk <<= 1) {
        unsigned long long o2 = __shfl_xor(pk, msk);
        pk = (o2 < pk) ? o2 : pk;
      }
      if (r == 0) atomicMin(&best[bm + wm * 64 + m * 16 + g * 4 + reg], pk);
    }
  }
}

// Fallback (small ws): exact fp32 squared distance, fused argmin.
__global__ __launch_bounds__(256) void naive_argmin_k(const float* __restrict__ A,
                                                      const float* __restrict__ B,
                                                      unsigned long long* __restrict__ best) {
  __shared__ float arow[ND];
  int p = blockIdx.y;
  unsigned v = blockIdx.x * 256 + threadIdx.x;
  for (int i = threadIdx.x; i < ND; i += 256) arow[i] = A[(size_t)p * ND + i];
  __syncthreads();
  const float4* br = (const float4*)(B + (size_t)v * ND);
  float s = 0.f;
#pragma unroll 4
  for (int i = 0; i < ND / 4; ++i) {
    float4 b = br[i];
    const float4 a = *(const float4*)&arow[i * 4];
    float d0 = a.x - b.x, d1 = a.y - b.y, d2 = a.z - b.z, d3 = a.w - b.w;
    s += d0 * d0 + d1 * d1 + d2 * d2 + d3 * d3;
  }
  unsigned long long pk = pack_sv(s, v);
#pragma unroll
  for (int msk = 1; msk < 64; msk <<= 1) {
    unsigned long long o = __shfl_xor(pk, msk);
    pk = (o < pk) ? o : pk;
  }
  if ((threadIdx.x & 63) == 0) atomicMin(&best[p], pk);
}

// Gather winning rows + ids (ids written as float, d_out is read as flat f32).
__global__ __launch_bounds__(128) void gather_k(const unsigned long long* __restrict__ best,
                                                const float* __restrict__ clip,
                                                float* __restrict__ out) {
  int p = blockIdx.x;
  unsigned long long pk = best[p];
  unsigned v = (unsigned)(pk & 0xffffffffull);
  const float4* src = (const float4*)(clip + (size_t)v * ND);
  float4* dst = (float4*)(out + (size_t)p * ND);
  dst[threadIdx.x] = src[threadIdx.x];
  if (threadIdx.x == 0) out[(size_t)NP * ND + p] = (float)v;
}

extern "C" void kernel_launch(void* const* d_in, const int* in_sizes, int n_in,
                              void* d_out, int out_size, void* d_ws, size_t ws_size,
                              hipStream_t stream) {
  const float* prompt = (const float*)d_in[0];
  const float* clip = (const float*)d_in[1];
  float* out = (float*)d_out;

  // workspace layout
  size_t off = 0;
  unsigned long long* best = (unsigned long long*)d_ws;
  off += (size_t)NP * 8;
  float* b2 = (float*)((char*)d_ws + off);
  off += (size_t)NV * 4;
  off = (off + 255) & ~(size_t)255;
  __bf16* Ap = (__bf16*)((char*)d_ws + off);
  off += (size_t)NP * 1024 * 2;                // 2 MiB  [hi|lo]
  __bf16* Bp = (__bf16*)((char*)d_ws + off);
  off += (size_t)NV * 1024 * 2;                // 96.5 MiB [hi|lo]
  const size_t need = off;

  if (ws_size >= need) {
    hipMemsetAsync(best, 0xFF, (size_t)NP * 8, stream);
    pack_rows_k<<<NP / 4, 256, 0, stream>>>(prompt, Ap, nullptr, NP);
    pack_rows_k<<<NV / 4, 256, 0, stream>>>(clip, Bp, b2, NV);
    gemm_argmin_k<<<dim3(8 * 386), 256, 0, stream>>>(Ap, Bp, b2, best);
    gather_k<<<NP, 128, 0, stream>>>(best, clip, out);
  } else {
    // fallback: exact fp32, needs only the 8 KiB `best` array
    hipMemsetAsync(best, 0xFF, (size_t)NP * 8, stream);
    dim3 grid(NV / 256, NP);
    naive_argmin_k<<<grid, 256, 0, stream>>>(prompt, clip, best);
    gather_k<<<NP, 128, 0, stream>>>(best, clip, out);
  }
}

// Round 13
// 225.533 us; speedup vs baseline: 3.7014x; 1.6843x over previous
//
#include <hip/hip_runtime.h>
#include <stdint.h>

#define NP 1024
#define NV 49408
#define ND 512
// B packed: [row][hi(512)|lo(512)] bf16 (2048 B/row).
// A packed FRAGMENT-ORDERED: chunk(t, mb, lane) at byte ((t*64+mb)*64+lane)*16
//   t = phys 32-k tile (0..31: 16 hi, 16 lo), mb = row>>4, lane = g*16+r holds
//   A[mb*16+r][t*32 + g*8 .. +7]. A wave's frag load = 1 KB contiguous.
// Logical K=1536, 3-term split, 32-k steps -> 48 tiles:
//   A phys tile = t & 31                  (ah x16, al x16, ah x16)
//   B phys byte = (t & 15) * 64 + (t >= 32 ? 1024 : 0)   (bh, bh, bl)
#define NTILE 48

typedef __attribute__((ext_vector_type(8))) __bf16 bf16x8;
typedef __attribute__((ext_vector_type(4))) float f32x4;
typedef __attribute__((ext_vector_type(4))) int i32x4;

__device__ inline unsigned long long pack_sv(float s, unsigned v) {
  unsigned u = __float_as_uint(s);
  u = (u & 0x80000000u) ? ~u : (u | 0x80000000u);  // orderable map
  return ((unsigned long long)u << 32) | (unsigned long long)v;
}

// A-pack: bf16 hi/lo split, FRAGMENT-ORDERED layout (see header comment).
// Lane's 8 source elems (k = lane*8..+7) are exactly chunk (t=lane>>2, g=lane&3).
__global__ __launch_bounds__(256) void pack_a_k(const float* __restrict__ src,
                                                __bf16* __restrict__ dst) {
  int lane = threadIdx.x & 63;
  int row = blockIdx.x * 4 + (threadIdx.x >> 6);
  const float* r = src + (size_t)row * ND + lane * 8;
  float4 x0 = *(const float4*)r;
  float4 x1 = *(const float4*)(r + 4);
  float xs[8] = {x0.x, x0.y, x0.z, x0.w, x1.x, x1.y, x1.z, x1.w};
  bf16x8 hi, lo;
#pragma unroll
  for (int j = 0; j < 8; ++j) {
    float x = xs[j];
    __bf16 h = (__bf16)x;
    hi[j] = h;
    lo[j] = (__bf16)(x - (float)h);   // exact residual, then RTNE to bf16
  }
  const int mb = row >> 4, rr = row & 15;
  const int tHi = lane >> 2, g = lane & 3;
  size_t cHi = (((size_t)tHi * 64) + mb) * 64 + g * 16 + rr;        // chunk idx
  size_t cLo = (((size_t)(tHi + 16) * 64) + mb) * 64 + g * 16 + rr;
  *(bf16x8*)(dst + cHi * 8) = hi;
  *(bf16x8*)(dst + cLo * 8) = lo;
}

// B-pack: [row][hi|lo] + exact f32 sum of squares per row.
__global__ __launch_bounds__(256) void pack_b_k(const float* __restrict__ src,
                                                __bf16* __restrict__ dst,
                                                float* __restrict__ sumsq) {
  int lane = threadIdx.x & 63;
  int row = blockIdx.x * 4 + (threadIdx.x >> 6);
  const float* r = src + (size_t)row * ND + lane * 8;
  float4 x0 = *(const float4*)r;
  float4 x1 = *(const float4*)(r + 4);
  float xs[8] = {x0.x, x0.y, x0.z, x0.w, x1.x, x1.y, x1.z, x1.w};
  bf16x8 hi, lo;
  float ss = 0.f;
#pragma unroll
  for (int j = 0; j < 8; ++j) {
    float x = xs[j];
    ss += x * x;
    __bf16 h = (__bf16)x;
    hi[j] = h;
    lo[j] = (__bf16)(x - (float)h);
  }
  __bf16* drow = dst + (size_t)row * 1024 + lane * 8;
  *(bf16x8*)drow = hi;
  *(bf16x8*)(drow + 512) = lo;
#pragma unroll
  for (int m = 1; m < 64; m <<= 1) ss += __shfl_xor(ss, m);
  if (lane == 0) sumsq[row] = ss;
}

// ---- 128x128 tile, BK=32, 4 waves, 3 blocks/CU, coalesced A-direct ---------
// Schedule = R10's (twice-verified absmax=0): per phase
//   [4x plain A-load(t+1), 1KB-contiguous each] [2x gll16 B(t+2) -> (p+2)%3]
//   [4x asm ds_read_b128 B(t) from p%3] [s_waitcnt vmcnt(6) lgkmcnt(0)]
//   [sched_barrier] [16 MFMA] [s_barrier].
// vmcnt(6) leaves this phase's 6 VMEM -> drains A(t) (compute source) and
// B-stage(t) (read at p+2, published by this barrier). lgkm0 BEFORE the
// barrier is load-bearing (R12 failed without it: WAR on region (p+2)%3).
// REGISTER BUDGET (R9): acc(64 AGPR)+frags vs UNIFIED file; (256,3) -> 170.
// B slot swizzle (R6-verified, 0 conflicts): 16B-slot
//   q(row,c16) = (row>>1)*8 + (row&1)*4 + ((c16 + (row>>1)) & 3)

__device__ __attribute__((always_inline)) static inline
void gll16(const char* src, char* dst) {
  __builtin_amdgcn_global_load_lds(
      (const __attribute__((address_space(1))) void*)src,
      (__attribute__((address_space(3))) void*)dst, 16, 0, 0);
}

__device__ __attribute__((always_inline)) static inline
bf16x8 lds_read(unsigned addr) {
  i32x4 d;
  asm volatile("ds_read_b128 %0, %1" : "=v"(d) : "v"(addr));
  return __builtin_bit_cast(bf16x8, d);
}

#define FENCE asm volatile("" ::: "memory")

template <int PH>
__device__ __attribute__((always_inline)) static inline
void phase_op(f32x4 (&acc)[4][4], bf16x8 (&aE)[4], bf16x8 (&aO)[4],
              const char* Ab, const int (&voffA)[4],
              const char* srcBt, char* stB, unsigned bRead, int p) {
  constexpr int R = PH % 3;
  constexpr int RS = (PH + 2) % 3;
  const int kA = ((p + 1) & 31) * 65536;                       // A tile p+1
  const int t2 = p + 2;
  const int kB = (t2 & 15) * 64 + (t2 >= 32 ? 1024 : 0);       // B tile p+2
  bf16x8 (&aN)[4] = (PH % 2 == 0) ? aO : aE;   // prefetch target
  bf16x8 (&aC)[4] = (PH % 2 == 0) ? aE : aO;   // compute source
  // A prefetch for next phase (plain loads, 1KB contiguous per frag)
#pragma unroll
  for (int m = 0; m < 4; ++m)
    aN[m] = *(const bf16x8*)(Ab + voffA[m] + kA);
  // B stage for phase p+2 (region RS died at phase p-1)
  gll16(srcBt + kB, stB + RS * 8192);
  gll16(srcBt + kB + 131072, stB + RS * 8192 + 4096);
  // B fragment reads for this phase
  bf16x8 b[4];
#pragma unroll
  for (int n = 0; n < 4; ++n)
    b[n] = lds_read(bRead + R * 8192 + n * 1024);
  asm volatile("s_waitcnt vmcnt(6) lgkmcnt(0)" ::: "memory");
  __builtin_amdgcn_sched_barrier(0);
  __builtin_amdgcn_s_setprio(1);
#pragma unroll
  for (int m = 0; m < 4; ++m)
#pragma unroll
    for (int n = 0; n < 4; ++n)
      acc[m][n] = __builtin_amdgcn_mfma_f32_16x16x32_bf16(aC[m], b[n], acc[m][n], 0, 0, 0);
  __builtin_amdgcn_s_setprio(0);
  FENCE;
  __builtin_amdgcn_s_barrier();
  FENCE;
}

__global__ __launch_bounds__(256, 3) void gemm_argmin_k(const __bf16* __restrict__ A,
                                                        const __bf16* __restrict__ B,
                                                        const float* __restrict__ b2,
                                                        unsigned long long* __restrict__ best) {
  __shared__ __align__(16) char lds[24576];
  const int tid = threadIdx.x;
  const int lane = tid & 63;
  const int wid = tid >> 6;   // 0..3
  const int wm = wid >> 1;    // 2 wave-rows (64 rows each)
  const int wn = wid & 1;     // 2 wave-cols (64 cols each)

  // XCD-chunk swizzle (3088 % 8 == 0 -> bijective): 8 M-blocks of a B-panel
  // land on one XCD -> panel fetched into L2 once (R6: FETCH 606->64 MB).
  const int d = blockIdx.x;
  const int o = (d & 7) * 386 + (d >> 3);
  const int bm = (o & 7) * 128;
  const int bn = (o >> 3) * 128;

  const int r = lane & 15, g = lane >> 4;
  const int rh = r >> 1;
  const unsigned lds0 =
      (unsigned)(uintptr_t)(const __attribute__((address_space(3))) char*)(const char*)lds;
  const unsigned bRead = lds0 + wn * 4096 + rh * 128 + (r & 1) * 64 + (((g + rh) & 3) << 4);

  // A per-lane byte offsets, fragment-ordered layout:
  // frag (wm,m) chunk base = ((bm>>4) + wm*4 + m)*1024, + lane*16 per lane
  const char* Ab = (const char*)A;
  int voffA[4];
#pragma unroll
  for (int m = 0; m < 4; ++m)
    voffA[m] = ((bm >> 4) + wm * 4 + m) * 1024 + lane * 16;

  // B stage-side lane mapping (inverse of the slot swizzle); 256 threads
  // cover 512 slots of the 8 KB region (rows 0-63 and +64 via 2nd gll16)
  const int srow = 2 * (tid >> 3) + ((tid >> 2) & 1);
  const int sc16 = ((tid & 3) - (tid >> 3)) & 3;
  const char* srcBt = (const char*)B + (size_t)(bn + srow) * 2048 + sc16 * 16;
  char* stB = (char*)lds + tid * 16;

  f32x4 acc[4][4] = {};
  bf16x8 aE[4], aO[4];

  // prologue: A(0) -> aE, Bstage(0)->R0, Bstage(1)->R1; drain to 2
#pragma unroll
  for (int m = 0; m < 4; ++m)
    aE[m] = *(const bf16x8*)(Ab + voffA[m]);
  gll16(srcBt + 0, stB + 0);
  gll16(srcBt + 0 + 131072, stB + 4096);
  gll16(srcBt + 64, stB + 8192);
  gll16(srcBt + 64 + 131072, stB + 8192 + 4096);
  asm volatile("s_waitcnt vmcnt(2)" ::: "memory");
  FENCE;
  __builtin_amdgcn_s_barrier();
  FENCE;

#pragma unroll 1
  for (int it = 0; it < 8; ++it) {
    const int p0 = 6 * it;
    phase_op<0>(acc, aE, aO, Ab, voffA, srcBt, stB, bRead, p0 + 0);
    phase_op<1>(acc, aE, aO, Ab, voffA, srcBt, stB, bRead, p0 + 1);
    phase_op<2>(acc, aE, aO, Ab, voffA, srcBt, stB, bRead, p0 + 2);
    phase_op<3>(acc, aE, aO, Ab, voffA, srcBt, stB, bRead, p0 + 3);
    phase_op<4>(acc, aE, aO, Ab, voffA, srcBt, stB, bRead, p0 + 4);
    phase_op<5>(acc, aE, aO, Ab, voffA, srcBt, stB, bRead, p0 + 5);
  }

  // epilogue: fused argmin. C/D map: col = lane&15, row = (lane>>4)*4 + reg.
  float bb[4];
#pragma unroll
  for (int n = 0; n < 4; ++n) bb[n] = b2[bn + wn * 64 + n * 16 + r];
#pragma unroll
  for (int m = 0; m < 4; ++m) {
#pragma unroll
    for (int reg = 0; reg < 4; ++reg) {
      unsigned long long pk = ~0ull;
#pragma unroll
      for (int n = 0; n < 4; ++n) {
        float s = bb[n] - 2.0f * acc[m][n][reg];
        unsigned long long cand = pack_sv(s, (unsigned)(bn + wn * 64 + n * 16 + r));
        pk = (cand < pk) ? cand : pk;
      }
#pragma unroll
      for (int msk = 1; msk < 16; msk <<= 1) {
        unsigned long long o2 = __shfl_xor(pk, msk);
        pk = (o2 < pk) ? o2 : pk;
      }
      if (r == 0) atomicMin(&best[bm + wm * 64 + m * 16 + g * 4 + reg], pk);
    }
  }
}

// Fallback (small ws): exact fp32 squared distance, fused argmin.
__global__ __launch_bounds__(256) void naive_argmin_k(const float* __restrict__ A,
                                                      const float* __restrict__ B,
                                                      unsigned long long* __restrict__ best) {
  __shared__ float arow[ND];
  int p = blockIdx.y;
  unsigned v = blockIdx.x * 256 + threadIdx.x;
  for (int i = threadIdx.x; i < ND; i += 256) arow[i] = A[(size_t)p * ND + i];
  __syncthreads();
  const float4* br = (const float4*)(B + (size_t)v * ND);
  float s = 0.f;
#pragma unroll 4
  for (int i = 0; i < ND / 4; ++i) {
    float4 b = br[i];
    const float4 a = *(const float4*)&arow[i * 4];
    float d0 = a.x - b.x, d1 = a.y - b.y, d2 = a.z - b.z, d3 = a.w - b.w;
    s += d0 * d0 + d1 * d1 + d2 * d2 + d3 * d3;
  }
  unsigned long long pk = pack_sv(s, v);
#pragma unroll
  for (int msk = 1; msk < 64; msk <<= 1) {
    unsigned long long o = __shfl_xor(pk, msk);
    pk = (o < pk) ? o : pk;
  }
  if ((threadIdx.x & 63) == 0) atomicMin(&best[p], pk);
}

// Gather winning rows + ids (ids written as float, d_out is read as flat f32).
__global__ __launch_bounds__(128) void gather_k(const unsigned long long* __restrict__ best,
                                                const float* __restrict__ clip,
                                                float* __restrict__ out) {
  int p = blockIdx.x;
  unsigned long long pk = best[p];
  unsigned v = (unsigned)(pk & 0xffffffffull);
  const float4* src = (const float4*)(clip + (size_t)v * ND);
  float4* dst = (float4*)(out + (size_t)p * ND);
  dst[threadIdx.x] = src[threadIdx.x];
  if (threadIdx.x == 0) out[(size_t)NP * ND + p] = (float)v;
}

extern "C" void kernel_launch(void* const* d_in, const int* in_sizes, int n_in,
                              void* d_out, int out_size, void* d_ws, size_t ws_size,
                              hipStream_t stream) {
  const float* prompt = (const float*)d_in[0];
  const float* clip = (const float*)d_in[1];
  float* out = (float*)d_out;

  // workspace layout
  size_t off = 0;
  unsigned long long* best = (unsigned long long*)d_ws;
  off += (size_t)NP * 8;
  float* b2 = (float*)((char*)d_ws + off);
  off += (size_t)NV * 4;
  off = (off + 255) & ~(size_t)255;
  __bf16* Ap = (__bf16*)((char*)d_ws + off);
  off += (size_t)NP * 1024 * 2;                // 2 MiB  fragment-ordered
  __bf16* Bp = (__bf16*)((char*)d_ws + off);
  off += (size_t)NV * 1024 * 2;                // 96.5 MiB [hi|lo]
  const size_t need = off;

  if (ws_size >= need) {
    hipMemsetAsync(best, 0xFF, (size_t)NP * 8, stream);
    pack_a_k<<<NP / 4, 256, 0, stream>>>(prompt, Ap);
    pack_b_k<<<NV / 4, 256, 0, stream>>>(clip, Bp, b2);
    gemm_argmin_k<<<dim3(8 * 386), 256, 0, stream>>>(Ap, Bp, b2, best);
    gather_k<<<NP, 128, 0, stream>>>(best, clip, out);
  } else {
    // fallback: exact fp32, needs only the 8 KiB `best` array
    hipMemsetAsync(best, 0xFF, (size_t)NP * 8, stream);
    dim3 grid(NV / 256, NP);
    naive_argmin_k<<<grid, 256, 0, stream>>>(prompt, clip, best);
    gather_k<<<NP, 128, 0, stream>>>(best, clip, out);
  }
}

// Round 14
// 222.716 us; speedup vs baseline: 3.7483x; 1.0126x over previous
//
#include <hip/hip_runtime.h>
#include <stdint.h>

#define NP 1024
#define NV 49408
#define ND 512
// B packed: [row][hi(512)|lo(512)] bf16 (2048 B/row).
// A packed FRAGMENT-ORDERED: chunk(t, mb, lane) at byte ((t*64+mb)*64+lane)*16
//   t = phys 32-k tile (0..31: 16 hi, 16 lo), mb = row>>4, lane = g*16+r holds
//   A[mb*16+r][t*32 + g*8 .. +7]. A wave's frag load = 1 KB contiguous.
// Logical K=1536, 3-term split, 32-k steps -> 48 tiles:
//   A phys tile = t & 31                  (ah x16, al x16, ah x16)
//   B phys byte = (t & 15) * 64 + (t >= 32 ? 1024 : 0)   (bh, bh, bl)
#define NTILE 48

typedef __attribute__((ext_vector_type(8))) __bf16 bf16x8;
typedef __attribute__((ext_vector_type(4))) float f32x4;
typedef __attribute__((ext_vector_type(4))) int i32x4;

__device__ inline unsigned long long pack_sv(float s, unsigned v) {
  unsigned u = __float_as_uint(s);
  u = (u & 0x80000000u) ? ~u : (u | 0x80000000u);  // orderable map
  return ((unsigned long long)u << 32) | (unsigned long long)v;
}

// A-pack: bf16 hi/lo split, FRAGMENT-ORDERED layout (see header comment).
__global__ __launch_bounds__(256) void pack_a_k(const float* __restrict__ src,
                                                __bf16* __restrict__ dst) {
  int lane = threadIdx.x & 63;
  int row = blockIdx.x * 4 + (threadIdx.x >> 6);
  const float* r = src + (size_t)row * ND + lane * 8;
  float4 x0 = *(const float4*)r;
  float4 x1 = *(const float4*)(r + 4);
  float xs[8] = {x0.x, x0.y, x0.z, x0.w, x1.x, x1.y, x1.z, x1.w};
  bf16x8 hi, lo;
#pragma unroll
  for (int j = 0; j < 8; ++j) {
    float x = xs[j];
    __bf16 h = (__bf16)x;
    hi[j] = h;
    lo[j] = (__bf16)(x - (float)h);   // exact residual, then RTNE to bf16
  }
  const int mb = row >> 4, rr = row & 15;
  const int tHi = lane >> 2, g = lane & 3;
  size_t cHi = (((size_t)tHi * 64) + mb) * 64 + g * 16 + rr;        // chunk idx
  size_t cLo = (((size_t)(tHi + 16) * 64) + mb) * 64 + g * 16 + rr;
  *(bf16x8*)(dst + cHi * 8) = hi;
  *(bf16x8*)(dst + cLo * 8) = lo;
}

// B-pack: [row][hi|lo] + exact f32 sum of squares per row.
__global__ __launch_bounds__(256) void pack_b_k(const float* __restrict__ src,
                                                __bf16* __restrict__ dst,
                                                float* __restrict__ sumsq) {
  int lane = threadIdx.x & 63;
  int row = blockIdx.x * 4 + (threadIdx.x >> 6);
  const float* r = src + (size_t)row * ND + lane * 8;
  float4 x0 = *(const float4*)r;
  float4 x1 = *(const float4*)(r + 4);
  float xs[8] = {x0.x, x0.y, x0.z, x0.w, x1.x, x1.y, x1.z, x1.w};
  bf16x8 hi, lo;
  float ss = 0.f;
#pragma unroll
  for (int j = 0; j < 8; ++j) {
    float x = xs[j];
    ss += x * x;
    __bf16 h = (__bf16)x;
    hi[j] = h;
    lo[j] = (__bf16)(x - (float)h);
  }
  __bf16* drow = dst + (size_t)row * 1024 + lane * 8;
  *(bf16x8*)drow = hi;
  *(bf16x8*)(drow + 512) = lo;
#pragma unroll
  for (int m = 1; m < 64; m <<= 1) ss += __shfl_xor(ss, m);
  if (lane == 0) sumsq[row] = ss;
}

// ---- 128x128 tile, BK=32, 4 waves, 3 blocks/CU, fully-pipelined ------------
// A: coalesced direct global->reg (R13), double-buffered 1 phase ahead.
// B: LDS 4 regions x 8 KB (region = tile & 3), stage depth 3; B FRAGMENTS
// double-buffered in registers, read 1 phase ahead. Per phase p:
//   [gll16 Bst(p+3) -> region (p+3)&3] [A-pref(p+1)] [ds_read B(p+1) from
//    region (p+1)&3] [s_waitcnt vmcnt(6) lgkmcnt(4)] [16 MFMA on A(p),B(p)]
//   [s_barrier].
// Both waits reference LAST phase's ops (full phase of slack -> ~0 stall):
//  vmcnt(6) leaves this phase's {Bst x2, A x4}; forces p-1's A(p) (consumed
//  now) and Bst(p+2) (published by this barrier, read at p+1).
//  lgkmcnt(4) leaves this phase's 4 ds_reads; forces p-1's B(p) frags.
// Hazards verified: Bst(t) issued at t-3, forced complete at t-2's vmcnt,
// published at barrier-(t-2), read at t-1, consumed at t; region WAR: last
// reads of a region finish by lgkmcnt at the next phase, one barrier before
// the overwriting stage issues. Wrap tiles 48-50: dead re-stage, never read.
// REGISTER BUDGET: acc(64 AGPR) + aE/aO(32) + bE/bO(32) + addr ~= 164 <= 170
// cap from (256,3). Watch WRITE_SIZE for spill.
// B slot swizzle (R6-verified, 0 conflicts): 16B-slot
//   q(row,c16) = (row>>1)*8 + (row&1)*4 + ((c16 + (row>>1)) & 3)

__device__ __attribute__((always_inline)) static inline
void gll16(const char* src, char* dst) {
  __builtin_amdgcn_global_load_lds(
      (const __attribute__((address_space(1))) void*)src,
      (__attribute__((address_space(3))) void*)dst, 16, 0, 0);
}

__device__ __attribute__((always_inline)) static inline
bf16x8 lds_read(unsigned addr) {
  i32x4 d;
  asm volatile("ds_read_b128 %0, %1" : "=v"(d) : "v"(addr));
  return __builtin_bit_cast(bf16x8, d);
}

#define FENCE asm volatile("" ::: "memory")

__device__ __attribute__((always_inline)) static inline
int bByte(int t) {                    // B phys byte for logical tile t (wraps)
  int tt = (t < NTILE) ? t : t - NTILE;
  return (tt & 15) * 64 + (tt >= 32 ? 1024 : 0);
}

template <int J>
__device__ __attribute__((always_inline)) static inline
void phase_op(f32x4 (&acc)[4][4], bf16x8 (&aE)[4], bf16x8 (&aO)[4],
              bf16x8 (&bE)[4], bf16x8 (&bO)[4],
              const char* Ab, const int (&voffA)[4],
              const char* srcBt, char* stB, unsigned bRead, int p) {
  constexpr int RS = (J + 3) & 3;   // stage region (tile p+3)
  constexpr int RR = (J + 1) & 3;   // frag-read region (tile p+1)
  const int kB = bByte(p + 3);
  const int kA = ((p + 1) & 31) * 65536;
  bf16x8 (&aN)[4] = (J % 2 == 0) ? aO : aE;   // prefetch target
  bf16x8 (&aC)[4] = (J % 2 == 0) ? aE : aO;   // compute source
  bf16x8 (&bN)[4] = (J % 2 == 0) ? bO : bE;
  bf16x8 (&bC)[4] = (J % 2 == 0) ? bE : bO;
  // B stage for phase p+3 (region RS: last reads finished by p-1's lgkm)
  gll16(srcBt + kB, stB + RS * 8192);
  gll16(srcBt + kB + 131072, stB + RS * 8192 + 4096);
  // A prefetch for next phase (1KB-contiguous per frag)
#pragma unroll
  for (int m = 0; m < 4; ++m)
    aN[m] = *(const bf16x8*)(Ab + voffA[m] + kA);
  // B fragment reads for NEXT phase (region published at barrier-(p-1))
#pragma unroll
  for (int n = 0; n < 4; ++n)
    bN[n] = lds_read(bRead + RR * 8192 + n * 1024);
  asm volatile("s_waitcnt vmcnt(6) lgkmcnt(4)" ::: "memory");
  __builtin_amdgcn_sched_barrier(0);
  __builtin_amdgcn_s_setprio(1);
#pragma unroll
  for (int m = 0; m < 4; ++m)
#pragma unroll
    for (int n = 0; n < 4; ++n)
      acc[m][n] = __builtin_amdgcn_mfma_f32_16x16x32_bf16(aC[m], bC[n], acc[m][n], 0, 0, 0);
  __builtin_amdgcn_s_setprio(0);
  FENCE;
  __builtin_amdgcn_s_barrier();
  FENCE;
}

__global__ __launch_bounds__(256, 3) void gemm_argmin_k(const __bf16* __restrict__ A,
                                                        const __bf16* __restrict__ B,
                                                        const float* __restrict__ b2,
                                                        unsigned long long* __restrict__ best) {
  __shared__ __align__(16) char lds[32768];
  const int tid = threadIdx.x;
  const int lane = tid & 63;
  const int wid = tid >> 6;   // 0..3
  const int wm = wid >> 1;    // 2 wave-rows (64 rows each)
  const int wn = wid & 1;     // 2 wave-cols (64 cols each)

  // XCD-chunk swizzle (3088 % 8 == 0 -> bijective): 8 M-blocks of a B-panel
  // land on one XCD -> panel fetched into L2 once (R6: FETCH 606->64 MB).
  const int d = blockIdx.x;
  const int o = (d & 7) * 386 + (d >> 3);
  const int bm = (o & 7) * 128;
  const int bn = (o >> 3) * 128;

  const int r = lane & 15, g = lane >> 4;
  const int rh = r >> 1;
  const unsigned lds0 =
      (unsigned)(uintptr_t)(const __attribute__((address_space(3))) char*)(const char*)lds;
  const unsigned bRead = lds0 + wn * 4096 + rh * 128 + (r & 1) * 64 + (((g + rh) & 3) << 4);

  // A per-lane byte offsets, fragment-ordered layout:
  const char* Ab = (const char*)A;
  int voffA[4];
#pragma unroll
  for (int m = 0; m < 4; ++m)
    voffA[m] = ((bm >> 4) + wm * 4 + m) * 1024 + lane * 16;

  // B stage-side lane mapping (inverse of the slot swizzle)
  const int srow = 2 * (tid >> 3) + ((tid >> 2) & 1);
  const int sc16 = ((tid & 3) - (tid >> 3)) & 3;
  const char* srcBt = (const char*)B + (size_t)(bn + srow) * 2048 + sc16 * 16;
  char* stB = (char*)lds + tid * 16;

  f32x4 acc[4][4] = {};
  bf16x8 aE[4], aO[4], bE[4], bO[4];

  // prologue: stage tiles 0,1,2 -> regions 0,1,2; A(0)->aE;
  // vmcnt(6) forces Bst0+Bst1 (needed for prologue read + phase-0 read);
  // barrier publishes; read B(0) frags -> bE.
  gll16(srcBt + bByte(0), stB + 0);
  gll16(srcBt + bByte(0) + 131072, stB + 4096);
  gll16(srcBt + bByte(1), stB + 8192);
  gll16(srcBt + bByte(1) + 131072, stB + 8192 + 4096);
  gll16(srcBt + bByte(2), stB + 16384);
  gll16(srcBt + bByte(2) + 131072, stB + 16384 + 4096);
#pragma unroll
  for (int m = 0; m < 4; ++m)
    aE[m] = *(const bf16x8*)(Ab + voffA[m]);
  asm volatile("s_waitcnt vmcnt(6)" ::: "memory");
  FENCE;
  __builtin_amdgcn_s_barrier();
  FENCE;
#pragma unroll
  for (int n = 0; n < 4; ++n)
    bE[n] = lds_read(bRead + n * 1024);

#pragma unroll 1
  for (int it = 0; it < 12; ++it) {
    const int p0 = 4 * it;
    phase_op<0>(acc, aE, aO, bE, bO, Ab, voffA, srcBt, stB, bRead, p0 + 0);
    phase_op<1>(acc, aE, aO, bE, bO, Ab, voffA, srcBt, stB, bRead, p0 + 1);
    phase_op<2>(acc, aE, aO, bE, bO, Ab, voffA, srcBt, stB, bRead, p0 + 2);
    phase_op<3>(acc, aE, aO, bE, bO, Ab, voffA, srcBt, stB, bRead, p0 + 3);
  }

  // epilogue: fused argmin. C/D map: col = lane&15, row = (lane>>4)*4 + reg.
  float bb[4];
#pragma unroll
  for (int n = 0; n < 4; ++n) bb[n] = b2[bn + wn * 64 + n * 16 + r];
#pragma unroll
  for (int m = 0; m < 4; ++m) {
#pragma unroll
    for (int reg = 0; reg < 4; ++reg) {
      unsigned long long pk = ~0ull;
#pragma unroll
      for (int n = 0; n < 4; ++n) {
        float s = bb[n] - 2.0f * acc[m][n][reg];
        unsigned long long cand = pack_sv(s, (unsigned)(bn + wn * 64 + n * 16 + r));
        pk = (cand < pk) ? cand : pk;
      }
#pragma unroll
      for (int msk = 1; msk < 16; msk <<= 1) {
        unsigned long long o2 = __shfl_xor(pk, msk);
        pk = (o2 < pk) ? o2 : pk;
      }
      if (r == 0) atomicMin(&best[bm + wm * 64 + m * 16 + g * 4 + reg], pk);
    }
  }
}

// Fallback (small ws): exact fp32 squared distance, fused argmin.
__global__ __launch_bounds__(256) void naive_argmin_k(const float* __restrict__ A,
                                                      const float* __restrict__ B,
                                                      unsigned long long* __restrict__ best) {
  __shared__ float arow[ND];
  int p = blockIdx.y;
  unsigned v = blockIdx.x * 256 + threadIdx.x;
  for (int i = threadIdx.x; i < ND; i += 256) arow[i] = A[(size_t)p * ND + i];
  __syncthreads();
  const float4* br = (const float4*)(B + (size_t)v * ND);
  float s = 0.f;
#pragma unroll 4
  for (int i = 0; i < ND / 4; ++i) {
    float4 b = br[i];
    const float4 a = *(const float4*)&arow[i * 4];
    float d0 = a.x - b.x, d1 = a.y - b.y, d2 = a.z - b.z, d3 = a.w - b.w;
    s += d0 * d0 + d1 * d1 + d2 * d2 + d3 * d3;
  }
  unsigned long long pk = pack_sv(s, v);
#pragma unroll
  for (int msk = 1; msk < 64; msk <<= 1) {
    unsigned long long o = __shfl_xor(pk, msk);
    pk = (o < pk) ? o : pk;
  }
  if ((threadIdx.x & 63) == 0) atomicMin(&best[p], pk);
}

// Gather winning rows + ids (ids written as float, d_out is read as flat f32).
__global__ __launch_bounds__(128) void gather_k(const unsigned long long* __restrict__ best,
                                                const float* __restrict__ clip,
                                                float* __restrict__ out) {
  int p = blockIdx.x;
  unsigned long long pk = best[p];
  unsigned v = (unsigned)(pk & 0xffffffffull);
  const float4* src = (const float4*)(clip + (size_t)v * ND);
  float4* dst = (float4*)(out + (size_t)p * ND);
  dst[threadIdx.x] = src[threadIdx.x];
  if (threadIdx.x == 0) out[(size_t)NP * ND + p] = (float)v;
}

extern "C" void kernel_launch(void* const* d_in, const int* in_sizes, int n_in,
                              void* d_out, int out_size, void* d_ws, size_t ws_size,
                              hipStream_t stream) {
  const float* prompt = (const float*)d_in[0];
  const float* clip = (const float*)d_in[1];
  float* out = (float*)d_out;

  // workspace layout
  size_t off = 0;
  unsigned long long* best = (unsigned long long*)d_ws;
  off += (size_t)NP * 8;
  float* b2 = (float*)((char*)d_ws + off);
  off += (size_t)NV * 4;
  off = (off + 255) & ~(size_t)255;
  __bf16* Ap = (__bf16*)((char*)d_ws + off);
  off += (size_t)NP * 1024 * 2;                // 2 MiB  fragment-ordered
  __bf16* Bp = (__bf16*)((char*)d_ws + off);
  off += (size_t)NV * 1024 * 2;                // 96.5 MiB [hi|lo]
  const size_t need = off;

  if (ws_size >= need) {
    hipMemsetAsync(best, 0xFF, (size_t)NP * 8, stream);
    pack_a_k<<<NP / 4, 256, 0, stream>>>(prompt, Ap);
    pack_b_k<<<NV / 4, 256, 0, stream>>>(clip, Bp, b2);
    gemm_argmin_k<<<dim3(8 * 386), 256, 0, stream>>>(Ap, Bp, b2, best);
    gather_k<<<NP, 128, 0, stream>>>(best, clip, out);
  } else {
    // fallback: exact fp32, needs only the 8 KiB `best` array
    hipMemsetAsync(best, 0xFF, (size_t)NP * 8, stream);
    dim3 grid(NV / 256, NP);
    naive_argmin_k<<<grid, 256, 0, stream>>>(prompt, clip, best);
    gather_k<<<NP, 128, 0, stream>>>(best, clip, out);
  }
}